// Round 8
// baseline (670.073 us; speedup 1.0000x reference)
//
#include <hip/hip_runtime.h>
#include <hip/hip_bf16.h>

// E71 Delta cell: T=2048, B=16, D=1024, N=128
// proj layout in ws: [t][b][512] f32, cols 0..127=k_hat (after norm pass),
// 128..255=v, 256..383=q, 384..511=bx

#define T_STEPS 2048
#define NB 16
#define ND 128
#define KD 1024
#define PSTRIDE 512

typedef __attribute__((ext_vector_type(4))) float f32x4;
typedef __attribute__((ext_vector_type(2))) float f32x2;
typedef __attribute__((ext_vector_type(8))) short short8v;

__device__ __forceinline__ unsigned short f2bf(float f) {
  union { float f; unsigned int u; } c; c.f = f;
  unsigned int u = c.u;
  unsigned int r = u + 0x7fffu + ((u >> 16) & 1u);   // round-to-nearest-even
  return (unsigned short)(r >> 16);
}

// ---------------------------------------------------------------------------
// Projection GEMM (unchanged, ~56us): bf16 MFMA, 128x128 tile, BK=64,
// XOR-swizzled LDS.
// ---------------------------------------------------------------------------
__global__ __launch_bounds__(256) void proj_gemm(
    const float* __restrict__ X,
    const float* __restrict__ Wk, const float* __restrict__ Wv,
    const float* __restrict__ Wq, const float* __restrict__ Wb,
    float* __restrict__ C)
{
  __shared__ unsigned short As[128 * 64];
  __shared__ unsigned short Bs[128 * 64];
  const int tid = threadIdx.x;
  const int bm = blockIdx.x;
  const int bn = blockIdx.y;
  const float* W = (bn == 0) ? Wk : ((bn == 1) ? Wv : ((bn == 2) ? Wq : Wb));
  const int lane = tid & 63;
  const int wave = tid >> 6;
  const int wr = wave >> 1, wc = wave & 1;

  f32x4 acc[4][4];
#pragma unroll
  for (int i = 0; i < 4; i++)
#pragma unroll
    for (int j = 0; j < 4; j++) acc[i][j] = (f32x4){0.f, 0.f, 0.f, 0.f};

  for (int k0 = 0; k0 < KD; k0 += 64) {
    __syncthreads();
#pragma unroll
    for (int c = 0; c < 4; c++) {
      const int g = tid + c * 256;
      const int row = g >> 3;
      const int ch = g & 7;
      const int pos = ((ch ^ (row & 7)) * 8);
      {
        const float* ga = X + (size_t)(bm * 128 + row) * KD + k0 + ch * 8;
        float4 f0 = *(const float4*)(ga);
        float4 f1 = *(const float4*)(ga + 4);
        union { unsigned short u[8]; short8v v; } pk2;
        pk2.u[0] = f2bf(f0.x); pk2.u[1] = f2bf(f0.y);
        pk2.u[2] = f2bf(f0.z); pk2.u[3] = f2bf(f0.w);
        pk2.u[4] = f2bf(f1.x); pk2.u[5] = f2bf(f1.y);
        pk2.u[6] = f2bf(f1.z); pk2.u[7] = f2bf(f1.w);
        *reinterpret_cast<short8v*>(&As[row * 64 + pos]) = pk2.v;
      }
      {
        const float* gb = W + (size_t)row * KD + k0 + ch * 8;
        float4 f0 = *(const float4*)(gb);
        float4 f1 = *(const float4*)(gb + 4);
        union { unsigned short u[8]; short8v v; } pk2;
        pk2.u[0] = f2bf(f0.x); pk2.u[1] = f2bf(f0.y);
        pk2.u[2] = f2bf(f0.z); pk2.u[3] = f2bf(f0.w);
        pk2.u[4] = f2bf(f1.x); pk2.u[5] = f2bf(f1.y);
        pk2.u[6] = f2bf(f1.z); pk2.u[7] = f2bf(f1.w);
        *reinterpret_cast<short8v*>(&Bs[row * 64 + pos]) = pk2.v;
      }
    }
    __syncthreads();
#pragma unroll
    for (int kk = 0; kk < 2; kk++) {
      const int ch = kk * 4 + (lane >> 4);
      short8v a[4], b[4];
#pragma unroll
      for (int i = 0; i < 4; i++) {
        const int ar = wr * 64 + i * 16 + (lane & 15);
        a[i] = *reinterpret_cast<const short8v*>(&As[ar * 64 + ((ch ^ (ar & 7)) * 8)]);
        const int br = wc * 64 + i * 16 + (lane & 15);
        b[i] = *reinterpret_cast<const short8v*>(&Bs[br * 64 + ((ch ^ (br & 7)) * 8)]);
      }
#pragma unroll
      for (int i = 0; i < 4; i++)
#pragma unroll
        for (int j = 0; j < 4; j++)
          acc[i][j] = __builtin_amdgcn_mfma_f32_16x16x32_bf16(a[i], b[j], acc[i][j], 0, 0, 0);
    }
  }
#pragma unroll
  for (int i = 0; i < 4; i++)
#pragma unroll
    for (int j = 0; j < 4; j++)
#pragma unroll
      for (int r = 0; r < 4; r++) {
        const int row = bm * 128 + wr * 64 + i * 16 + (lane >> 4) * 4 + r;
        const int col = bn * 128 + wc * 64 + j * 16 + (lane & 15);
        C[(size_t)row * PSTRIDE + col] = acc[i][j][r];
      }
}

// ---------------------------------------------------------------------------
// k-normalization pre-pass: proj[row][0:128] <- k / (||k|| + eps).
// ---------------------------------------------------------------------------
__global__ __launch_bounds__(256) void norm_k(float* __restrict__ proj) {
  const int lane = threadIdx.x & 63;
  const int wid = (blockIdx.x * 256 + threadIdx.x) >> 6;
  float* rowp = proj + (size_t)wid * PSTRIDE;
  float2 kv = *reinterpret_cast<float2*>(rowp + lane * 2);
  float ss = kv.x * kv.x + kv.y * kv.y;
  ss += __shfl_xor(ss, 1);
  ss += __shfl_xor(ss, 2);
  ss += __shfl_xor(ss, 4);
  ss += __shfl_xor(ss, 8);
  ss += __shfl_xor(ss, 16);
  ss += __shfl_xor(ss, 32);
  const float rn = 1.0f / (sqrtf(ss) + 1e-6f);
  kv.x *= rn; kv.y *= rn;
  *reinterpret_cast<float2*>(rowp + lane * 2) = kv;
}

// ---------------------------------------------------------------------------
// Sequential scan, pure-register, zero LDS/DS ops, zero barriers.
// R8 geometry: 64 blocks x 512 threads (8 waves). Block = (batch, sub);
//   wave wv handles row-group grp = sub*8+wv. -> 64 CUs x 8 waves =
//   2 chains per SIMD: while one chain stalls (chain dep / vmcnt), the
//   other issues (the R7 stall was ~300cy/step with nothing co-resident).
//   All 8 waves of a block read the SAME 2KB proj row per step -> L1 dedupe;
//   the 4 blocks of a batch land on one XCD (bid%8 = batch%8) -> L2 share.
// Lane map: 16 lanes/row (cc = lane&15 -> 8 cols), rloc = lane>>4.
// Depth-8 asm-prefetch ring (inline asm loads cannot be sunk by IR passes;
// R4/R6's plain loads were). Counted s_waitcnt vmcnt(42): 42 = 7 bufs x 6
// loads; in-order vmcnt retirement => consumed buf complete (stores only
// add younger ops). sched_barrier(0) after each wait (rule #18).
// Reduction: all-DPP rotation reduce row_ror:8/4/2/1. silu+store deferred.
// __launch_bounds__(512, 2): VGPR cap 256 (need ~190; R5's crush was cap 64).
// ---------------------------------------------------------------------------
__device__ __forceinline__ float sum16r(float v) {
  v += __int_as_float(__builtin_amdgcn_update_dpp(0, __float_as_int(v), 0x128, 0xF, 0xF, true)); // row_ror:8
  v += __int_as_float(__builtin_amdgcn_update_dpp(0, __float_as_int(v), 0x124, 0xF, 0xF, true)); // row_ror:4
  v += __int_as_float(__builtin_amdgcn_update_dpp(0, __float_as_int(v), 0x122, 0xF, 0xF, true)); // row_ror:2
  v += __int_as_float(__builtin_amdgcn_update_dpp(0, __float_as_int(v), 0x121, 0xF, 0xF, true)); // row_ror:1
  return v;
}

struct Buf { f32x4 kn0, kn1, q0, q1; float v, bx; };

// pk = row base + cc*8 floats; pv = row base + row (scalar lane base).
// k at +0,+16B; q at +1024,+1040B; v at +512B; bx at +1536B (13-bit imm ok).
__device__ __forceinline__ void load_buf_asm(const float* pk, const float* pv, Buf& b) {
  asm volatile("global_load_dwordx4 %0, %1, off"             : "=v"(b.kn0) : "v"(pk));
  asm volatile("global_load_dwordx4 %0, %1, off offset:16"   : "=v"(b.kn1) : "v"(pk));
  asm volatile("global_load_dwordx4 %0, %1, off offset:1024" : "=v"(b.q0)  : "v"(pk));
  asm volatile("global_load_dwordx4 %0, %1, off offset:1040" : "=v"(b.q1)  : "v"(pk));
  asm volatile("global_load_dword %0, %1, off offset:512"    : "=v"(b.v)   : "v"(pv));
  asm volatile("global_load_dword %0, %1, off offset:1536"   : "=v"(b.bx)  : "v"(pv));
}

__device__ __forceinline__ float core(const Buf& b, float db, float bb, f32x2 S2[4]) {
  const f32x2 k0 = {b.kn0.x, b.kn0.y}, k1 = {b.kn0.z, b.kn0.w};
  const f32x2 k2 = {b.kn1.x, b.kn1.y}, k3 = {b.kn1.z, b.kn1.w};
  f32x2 a0 = S2[0] * k0;
  f32x2 a1 = S2[1] * k1;
  a0 = __builtin_elementwise_fma(S2[2], k2, a0);
  a1 = __builtin_elementwise_fma(S2[3], k3, a1);
  const f32x2 ac = a0 + a1;
  const float r = sum16r(ac.x + ac.y);
  const float lg = fmaf(db, r, b.bx + bb);
  const float beta = __builtin_amdgcn_rcpf(1.0f + __expf(-lg));
  const float cr = beta * (b.v - r);
  const f32x2 cr2 = {cr, cr};
  S2[0] = __builtin_elementwise_fma(cr2, k0, S2[0]);
  S2[1] = __builtin_elementwise_fma(cr2, k1, S2[1]);
  S2[2] = __builtin_elementwise_fma(cr2, k2, S2[2]);
  S2[3] = __builtin_elementwise_fma(cr2, k3, S2[3]);
  const f32x2 q0 = {b.q0.x, b.q0.y}, q1 = {b.q0.z, b.q0.w};
  const f32x2 q2 = {b.q1.x, b.q1.y}, q3 = {b.q1.z, b.q1.w};
  f32x2 o0 = S2[0] * q0;
  f32x2 o1 = S2[1] * q1;
  o0 = __builtin_elementwise_fma(S2[2], q2, o0);
  o1 = __builtin_elementwise_fma(S2[3], q3, o1);
  const f32x2 ao = o0 + o1;
  return sum16r(ao.x + ao.y);                      // raw od; silu deferred
}

__device__ __forceinline__ float fin(float od) {
  return od * od * __builtin_amdgcn_rcpf(1.0f + __expf(-od));
}

__global__ __launch_bounds__(512, 2) void scan_kernel(
    const float* __restrict__ proj, const float* __restrict__ S_in,
    const float* __restrict__ d_beta, const float* __restrict__ b_beta,
    float* __restrict__ out, float* __restrict__ S_out)
{
  const int tid = threadIdx.x;
  const int lane = tid & 63;
  const int wv = tid >> 6;                 // 0..7 wave in block
  const int batch = blockIdx.x & 15;       // 4 blocks of a batch share XCD b%8
  const int sub = blockIdx.x >> 4;         // 0..3
  const int grp = sub * 8 + wv;            // 0..31 row-group of 4
  const int cc = lane & 15;                // col chunk: 8 floats
  const int rloc = lane >> 4;              // 0..3
  const int row = grp * 4 + rloc;
  const bool w0 = (cc == 0);               // one lane per row stores

  f32x2 S2[4];
  {
    const f32x4* Sp4 = reinterpret_cast<const f32x4*>(
        S_in + ((size_t)batch * ND + row) * ND + cc * 8);
    const f32x4 s0 = Sp4[0], s1 = Sp4[1];
    S2[0] = (f32x2){s0.x, s0.y}; S2[1] = (f32x2){s0.z, s0.w};
    S2[2] = (f32x2){s1.x, s1.y}; S2[3] = (f32x2){s1.z, s1.w};
  }
  const float db = d_beta[row];
  const float bb = b_beta[row];

  const float* pb = proj + (size_t)batch * PSTRIDE;
  const float* pkb = pb + cc * 8;          // vector lane base
  const float* pvb = pb + row;             // scalar lane base
  const size_t sstep = (size_t)NB * PSTRIDE;
  float* outp = out + (size_t)batch * ND + row;
  const size_t ostep = (size_t)NB * ND;

  Buf B0, B1, B2, B3, B4, B5, B6, B7;
  load_buf_asm(pkb + 0 * sstep, pvb + 0 * sstep, B0);
  load_buf_asm(pkb + 1 * sstep, pvb + 1 * sstep, B1);
  load_buf_asm(pkb + 2 * sstep, pvb + 2 * sstep, B2);
  load_buf_asm(pkb + 3 * sstep, pvb + 3 * sstep, B3);
  load_buf_asm(pkb + 4 * sstep, pvb + 4 * sstep, B4);
  load_buf_asm(pkb + 5 * sstep, pvb + 5 * sstep, B5);
  load_buf_asm(pkb + 6 * sstep, pvb + 6 * sstep, B6);
  load_buf_asm(pkb + 7 * sstep, pvb + 7 * sstep, B7);

  float od_prev;

#define WAIT42 do { asm volatile("s_waitcnt vmcnt(42)" ::: "memory"); \
                    __builtin_amdgcn_sched_barrier(0); } while (0)

#define SLOT(BUF, tnext)                                                  \
  do {                                                                    \
    const float gprev = fin(od_prev);                                     \
    if (w0) *outp = gprev;                                                \
    outp += ostep;                                                        \
    WAIT42;                                                               \
    od_prev = core(BUF, db, bb, S2);                                      \
    __builtin_amdgcn_sched_barrier(0);                                    \
    load_buf_asm(pkb + (size_t)(tnext) * sstep,                           \
                 pvb + (size_t)(tnext) * sstep, BUF);                     \
    __builtin_amdgcn_sched_barrier(0);                                    \
  } while (0)

  // peel: step 0 (no pending store)
  WAIT42;
  od_prev = core(B0, db, bb, S2);
  __builtin_amdgcn_sched_barrier(0);
  load_buf_asm(pkb + 8 * sstep, pvb + 8 * sstep, B0);
  __builtin_amdgcn_sched_barrier(0);
  SLOT(B1, 9);
  SLOT(B2, 10);
  SLOT(B3, 11);
  SLOT(B4, 12);
  SLOT(B5, 13);
  SLOT(B6, 14);
  SLOT(B7, 15);

  // steady state: steps 8..2039, loads up to 2047
  for (int t = 8; t + 16 <= T_STEPS; t += 8) {
    SLOT(B0, t + 8);
    SLOT(B1, t + 9);
    SLOT(B2, t + 10);
    SLOT(B3, t + 11);
    SLOT(B4, t + 12);
    SLOT(B5, t + 13);
    SLOT(B6, t + 14);
    SLOT(B7, t + 15);
  }

  // tail: steps 2040..2047, no further loads; drain once
  {
    const float g = fin(od_prev);
    if (w0) *outp = g;
    outp += ostep;
  }
  asm volatile("s_waitcnt vmcnt(0)" ::: "memory");
  __builtin_amdgcn_sched_barrier(0);
#define TAILSTEP(BUF)                                                     \
  do {                                                                    \
    od_prev = core(BUF, db, bb, S2);                                      \
    const float g = fin(od_prev);                                         \
    if (w0) *outp = g;                                                    \
    outp += ostep;                                                        \
  } while (0)
  TAILSTEP(B0);
  TAILSTEP(B1);
  TAILSTEP(B2);
  TAILSTEP(B3);
  TAILSTEP(B4);
  TAILSTEP(B5);
  TAILSTEP(B6);
  TAILSTEP(B7);
#undef TAILSTEP
#undef SLOT
#undef WAIT42

  {
    f32x4* So4 = reinterpret_cast<f32x4*>(
        S_out + ((size_t)batch * ND + row) * ND + cc * 8);
    f32x4 s0, s1;
    s0.x = S2[0].x; s0.y = S2[0].y; s0.z = S2[1].x; s0.w = S2[1].y;
    s1.x = S2[2].x; s1.y = S2[2].y; s1.z = S2[3].x; s1.w = S2[3].y;
    So4[0] = s0; So4[1] = s1;
  }
}

extern "C" void kernel_launch(void* const* d_in, const int* in_sizes, int n_in,
                              void* d_out, int out_size, void* d_ws, size_t ws_size,
                              hipStream_t stream) {
  const float* x  = (const float*)d_in[0];   // [2048][16][1024]
  const float* S0 = (const float*)d_in[1];   // [16][128][128]
  const float* Wk = (const float*)d_in[2];
  const float* Wv = (const float*)d_in[3];
  const float* Wq = (const float*)d_in[4];
  const float* Wb = (const float*)d_in[5];
  const float* db = (const float*)d_in[6];
  const float* bb = (const float*)d_in[7];
  float* out  = (float*)d_out;                           // [2048][16][128]
  float* Sout = out + (size_t)T_STEPS * NB * ND;         // [16][128][128]
  float* proj = (float*)d_ws;                            // [32768][512] = 64 MB

  dim3 ggrid(256, 4);
  proj_gemm<<<ggrid, 256, 0, stream>>>(x, Wk, Wv, Wq, Wb, proj);
  norm_k<<<8192, 256, 0, stream>>>(proj);
  scan_kernel<<<64, 512, 0, stream>>>(proj, S0, db, bb, out, Sout);
}

// Round 9
// 425.996 us; speedup vs baseline: 1.5730x; 1.5730x over previous
//
#include <hip/hip_runtime.h>
#include <hip/hip_bf16.h>

// E71 Delta cell: T=2048, B=16, D=1024, N=128
// proj layout in ws: [t][b][512] f32, cols 0..127=k_hat (after norm pass),
// 128..255=v, 256..383=q, 384..511=bx

#define T_STEPS 2048
#define NB 16
#define ND 128
#define KD 1024
#define PSTRIDE 512

typedef __attribute__((ext_vector_type(4))) float f32x4;
typedef __attribute__((ext_vector_type(2))) float f32x2;
typedef __attribute__((ext_vector_type(8))) short short8v;

__device__ __forceinline__ unsigned short f2bf(float f) {
  union { float f; unsigned int u; } c; c.f = f;
  unsigned int u = c.u;
  unsigned int r = u + 0x7fffu + ((u >> 16) & 1u);   // round-to-nearest-even
  return (unsigned short)(r >> 16);
}

// ---------------------------------------------------------------------------
// Projection GEMM (unchanged, ~56us): bf16 MFMA, 128x128 tile, BK=64,
// XOR-swizzled LDS.
// ---------------------------------------------------------------------------
__global__ __launch_bounds__(256) void proj_gemm(
    const float* __restrict__ X,
    const float* __restrict__ Wk, const float* __restrict__ Wv,
    const float* __restrict__ Wq, const float* __restrict__ Wb,
    float* __restrict__ C)
{
  __shared__ unsigned short As[128 * 64];
  __shared__ unsigned short Bs[128 * 64];
  const int tid = threadIdx.x;
  const int bm = blockIdx.x;
  const int bn = blockIdx.y;
  const float* W = (bn == 0) ? Wk : ((bn == 1) ? Wv : ((bn == 2) ? Wq : Wb));
  const int lane = tid & 63;
  const int wave = tid >> 6;
  const int wr = wave >> 1, wc = wave & 1;

  f32x4 acc[4][4];
#pragma unroll
  for (int i = 0; i < 4; i++)
#pragma unroll
    for (int j = 0; j < 4; j++) acc[i][j] = (f32x4){0.f, 0.f, 0.f, 0.f};

  for (int k0 = 0; k0 < KD; k0 += 64) {
    __syncthreads();
#pragma unroll
    for (int c = 0; c < 4; c++) {
      const int g = tid + c * 256;
      const int row = g >> 3;
      const int ch = g & 7;
      const int pos = ((ch ^ (row & 7)) * 8);
      {
        const float* ga = X + (size_t)(bm * 128 + row) * KD + k0 + ch * 8;
        float4 f0 = *(const float4*)(ga);
        float4 f1 = *(const float4*)(ga + 4);
        union { unsigned short u[8]; short8v v; } pk2;
        pk2.u[0] = f2bf(f0.x); pk2.u[1] = f2bf(f0.y);
        pk2.u[2] = f2bf(f0.z); pk2.u[3] = f2bf(f0.w);
        pk2.u[4] = f2bf(f1.x); pk2.u[5] = f2bf(f1.y);
        pk2.u[6] = f2bf(f1.z); pk2.u[7] = f2bf(f1.w);
        *reinterpret_cast<short8v*>(&As[row * 64 + pos]) = pk2.v;
      }
      {
        const float* gb = W + (size_t)row * KD + k0 + ch * 8;
        float4 f0 = *(const float4*)(gb);
        float4 f1 = *(const float4*)(gb + 4);
        union { unsigned short u[8]; short8v v; } pk2;
        pk2.u[0] = f2bf(f0.x); pk2.u[1] = f2bf(f0.y);
        pk2.u[2] = f2bf(f0.z); pk2.u[3] = f2bf(f0.w);
        pk2.u[4] = f2bf(f1.x); pk2.u[5] = f2bf(f1.y);
        pk2.u[6] = f2bf(f1.z); pk2.u[7] = f2bf(f1.w);
        *reinterpret_cast<short8v*>(&Bs[row * 64 + pos]) = pk2.v;
      }
    }
    __syncthreads();
#pragma unroll
    for (int kk = 0; kk < 2; kk++) {
      const int ch = kk * 4 + (lane >> 4);
      short8v a[4], b[4];
#pragma unroll
      for (int i = 0; i < 4; i++) {
        const int ar = wr * 64 + i * 16 + (lane & 15);
        a[i] = *reinterpret_cast<const short8v*>(&As[ar * 64 + ((ch ^ (ar & 7)) * 8)]);
        const int br = wc * 64 + i * 16 + (lane & 15);
        b[i] = *reinterpret_cast<const short8v*>(&Bs[br * 64 + ((ch ^ (br & 7)) * 8)]);
      }
#pragma unroll
      for (int i = 0; i < 4; i++)
#pragma unroll
        for (int j = 0; j < 4; j++)
          acc[i][j] = __builtin_amdgcn_mfma_f32_16x16x32_bf16(a[i], b[j], acc[i][j], 0, 0, 0);
    }
  }
#pragma unroll
  for (int i = 0; i < 4; i++)
#pragma unroll
    for (int j = 0; j < 4; j++)
#pragma unroll
      for (int r = 0; r < 4; r++) {
        const int row = bm * 128 + wr * 64 + i * 16 + (lane >> 4) * 4 + r;
        const int col = bn * 128 + wc * 64 + j * 16 + (lane & 15);
        C[(size_t)row * PSTRIDE + col] = acc[i][j][r];
      }
}

// ---------------------------------------------------------------------------
// k-normalization pre-pass: proj[row][0:128] <- k / (||k|| + eps).
// ---------------------------------------------------------------------------
__global__ __launch_bounds__(256) void norm_k(float* __restrict__ proj) {
  const int lane = threadIdx.x & 63;
  const int wid = (blockIdx.x * 256 + threadIdx.x) >> 6;
  float* rowp = proj + (size_t)wid * PSTRIDE;
  float2 kv = *reinterpret_cast<float2*>(rowp + lane * 2);
  float ss = kv.x * kv.x + kv.y * kv.y;
  ss += __shfl_xor(ss, 1);
  ss += __shfl_xor(ss, 2);
  ss += __shfl_xor(ss, 4);
  ss += __shfl_xor(ss, 8);
  ss += __shfl_xor(ss, 16);
  ss += __shfl_xor(ss, 32);
  const float rn = 1.0f / (sqrtf(ss) + 1e-6f);
  kv.x *= rn; kv.y *= rn;
  *reinterpret_cast<float2*>(rowp + lane * 2) = kv;
}

// ---------------------------------------------------------------------------
// Sequential scan, chain-decoupled (delta-rule identity):
//   r_{t+1}  = S(t)k_{t+1} + cr_t (k_t.k_{t+1})   [dots off-chain]
//   od_t     = S(t)q_t     + cr_t (k_t.q_t)       [dots off-chain]
// Serial chain per step: fma -> sigmoid -> cr  (~40cy), hidden under issue.
// Geometry (R7, best measured): 512 blocks x 64 thr; block = (batch, 4-row
// group); 16 lanes/row (cc = lane&15 -> 8 cols), rloc = lane>>4.
// Depth-8 asm-prefetch ring; uniform s_waitcnt vmcnt(36): drains exactly one
// buf batch + store per slot (7-slot ~1000cy cover; nxt buf guaranteed).
// Reduction: all-DPP rotation reduce row_ror:8/4/2/1 (off-chain now).
// ---------------------------------------------------------------------------
__device__ __forceinline__ float sum16r(float v) {
  v += __int_as_float(__builtin_amdgcn_update_dpp(0, __float_as_int(v), 0x128, 0xF, 0xF, true)); // row_ror:8
  v += __int_as_float(__builtin_amdgcn_update_dpp(0, __float_as_int(v), 0x124, 0xF, 0xF, true)); // row_ror:4
  v += __int_as_float(__builtin_amdgcn_update_dpp(0, __float_as_int(v), 0x122, 0xF, 0xF, true)); // row_ror:2
  v += __int_as_float(__builtin_amdgcn_update_dpp(0, __float_as_int(v), 0x121, 0xF, 0xF, true)); // row_ror:1
  return v;
}

struct Buf { f32x4 kn0, kn1, q0, q1; float v, bx; };

// pk = row base + cc*8 floats; pv = row base + row (scalar lane base).
// k at +0,+16B; q at +1024,+1040B; v at +512B; bx at +1536B (13-bit imm ok).
__device__ __forceinline__ void load_buf_asm(const float* pk, const float* pv, Buf& b) {
  asm volatile("global_load_dwordx4 %0, %1, off"             : "=v"(b.kn0) : "v"(pk));
  asm volatile("global_load_dwordx4 %0, %1, off offset:16"   : "=v"(b.kn1) : "v"(pk));
  asm volatile("global_load_dwordx4 %0, %1, off offset:1024" : "=v"(b.q0)  : "v"(pk));
  asm volatile("global_load_dwordx4 %0, %1, off offset:1040" : "=v"(b.q1)  : "v"(pk));
  asm volatile("global_load_dword %0, %1, off offset:512"    : "=v"(b.v)   : "v"(pv));
  asm volatile("global_load_dword %0, %1, off offset:1536"   : "=v"(b.bx)  : "v"(pv));
}

// dot of two 8-float lane slices held as f32x4 pairs -> lane-partial scalar
__device__ __forceinline__ float dot8(const f32x4& a0, const f32x4& a1,
                                      const f32x4& b0, const f32x4& b1) {
  const f32x2 ax = {a0.x, a0.y}, ay = {a0.z, a0.w}, az = {a1.x, a1.y}, aw = {a1.z, a1.w};
  const f32x2 bx = {b0.x, b0.y}, by = {b0.z, b0.w}, bz = {b1.x, b1.y}, bw = {b1.z, b1.w};
  f32x2 p = ax * bx;
  f32x2 q = ay * by;
  p = __builtin_elementwise_fma(az, bz, p);
  q = __builtin_elementwise_fma(aw, bw, q);
  const f32x2 s = p + q;
  return s.x + s.y;
}

__device__ __forceinline__ float dot8S(const f32x2 S2[4], const f32x4& b0, const f32x4& b1) {
  const f32x2 bx = {b0.x, b0.y}, by = {b0.z, b0.w}, bz = {b1.x, b1.y}, bw = {b1.z, b1.w};
  f32x2 p = S2[0] * bx;
  f32x2 q = S2[1] * by;
  p = __builtin_elementwise_fma(S2[2], bz, p);
  q = __builtin_elementwise_fma(S2[3], bw, q);
  const f32x2 s = p + q;
  return s.x + s.y;
}

__device__ __forceinline__ float fin(float od) {
  return od * od * __builtin_amdgcn_rcpf(1.0f + __expf(-od));
}

__global__ __launch_bounds__(64) void scan_kernel(
    const float* __restrict__ proj, const float* __restrict__ S_in,
    const float* __restrict__ d_beta, const float* __restrict__ b_beta,
    float* __restrict__ out, float* __restrict__ S_out)
{
  const int lane = threadIdx.x & 63;
  const int batch = blockIdx.x & 15;       // batches b, b+8 share XCD b%8
  const int grp = blockIdx.x >> 4;         // 0..31 row-group of 4
  const int cc = lane & 15;                // col chunk: 8 floats
  const int rloc = lane >> 4;              // 0..3
  const int row = grp * 4 + rloc;
  const bool w0 = (cc == 0);               // one lane per row stores

  f32x2 S2[4];
  {
    const f32x4* Sp4 = reinterpret_cast<const f32x4*>(
        S_in + ((size_t)batch * ND + row) * ND + cc * 8);
    const f32x4 s0 = Sp4[0], s1 = Sp4[1];
    S2[0] = (f32x2){s0.x, s0.y}; S2[1] = (f32x2){s0.z, s0.w};
    S2[2] = (f32x2){s1.x, s1.y}; S2[3] = (f32x2){s1.z, s1.w};
  }
  const float db = d_beta[row];
  const float bb = b_beta[row];

  const float* pb = proj + (size_t)batch * PSTRIDE;
  const float* pkb = pb + cc * 8;          // vector lane base
  const float* pvb = pb + row;             // scalar lane base
  const size_t sstep = (size_t)NB * PSTRIDE;
  float* outp = out + (size_t)batch * ND + row;
  const size_t ostep = (size_t)NB * ND;

  Buf B0, B1, B2, B3, B4, B5, B6, B7;
  load_buf_asm(pkb + 0 * sstep, pvb + 0 * sstep, B0);
  load_buf_asm(pkb + 1 * sstep, pvb + 1 * sstep, B1);
  load_buf_asm(pkb + 2 * sstep, pvb + 2 * sstep, B2);
  load_buf_asm(pkb + 3 * sstep, pvb + 3 * sstep, B3);
  load_buf_asm(pkb + 4 * sstep, pvb + 4 * sstep, B4);
  load_buf_asm(pkb + 5 * sstep, pvb + 5 * sstep, B5);
  load_buf_asm(pkb + 6 * sstep, pvb + 6 * sstep, B6);
  load_buf_asm(pkb + 7 * sstep, pvb + 7 * sstep, B7);

#define WAIT36 do { asm volatile("s_waitcnt vmcnt(36)" ::: "memory"); \
                    __builtin_amdgcn_sched_barrier(0); } while (0)

  // prologue: B0,B1 ready (48 outstanding -> 36 drains exactly B0,B1)
  WAIT36;
  float pre0 = sum16r(dot8S(S2, B0.kn0, B0.kn1));   // r_0 = S0.k0, no correction
  float kkp = 0.f, crp = 0.f;

#define SLOT(CUR, NXT, tnext)                                             \
  do {                                                                    \
    WAIT36;                                                               \
    /* off-chain dots (CUR, NXT guaranteed resident) */                   \
    const float d_pre = dot8S(S2, NXT.kn0, NXT.kn1);                      \
    const float d_sq  = dot8S(S2, CUR.q0, CUR.q1);                        \
    const float d_kk  = dot8(CUR.kn0, CUR.kn1, NXT.kn0, NXT.kn1);         \
    const float d_kq  = dot8(CUR.kn0, CUR.kn1, CUR.q0, CUR.q1);           \
    const float pre1 = sum16r(d_pre);                                     \
    const float Sq   = sum16r(d_sq);                                      \
    const float kk   = sum16r(d_kk);                                      \
    const float kq   = sum16r(d_kq);                                      \
    /* serial chain */                                                    \
    const float r  = fmaf(crp, kkp, pre0);                                \
    const float lg = fmaf(db, r, CUR.bx + bb);                            \
    const float beta = __builtin_amdgcn_rcpf(1.0f + __expf(-lg));         \
    const float cr = beta * (CUR.v - r);                                  \
    /* output (off-chain terminal) */                                     \
    const float od = fmaf(cr, kq, Sq);                                    \
    if (w0) *outp = fin(od);                                              \
    outp += ostep;                                                        \
    /* S update */                                                        \
    {                                                                     \
      const f32x2 cr2 = {cr, cr};                                         \
      const f32x2 kx = {CUR.kn0.x, CUR.kn0.y}, ky = {CUR.kn0.z, CUR.kn0.w}; \
      const f32x2 kz = {CUR.kn1.x, CUR.kn1.y}, kw = {CUR.kn1.z, CUR.kn1.w}; \
      S2[0] = __builtin_elementwise_fma(cr2, kx, S2[0]);                  \
      S2[1] = __builtin_elementwise_fma(cr2, ky, S2[1]);                  \
      S2[2] = __builtin_elementwise_fma(cr2, kz, S2[2]);                  \
      S2[3] = __builtin_elementwise_fma(cr2, kw, S2[3]);                  \
    }                                                                     \
    pre0 = pre1; kkp = kk; crp = cr;                                      \
    load_buf_asm(pkb + (size_t)(tnext) * sstep,                           \
                 pvb + (size_t)(tnext) * sstep, CUR);                     \
  } while (0)

  for (int t = 0; t < T_STEPS; t += 8) {
    const int t0 = (t +  8 < T_STEPS) ? t +  8 : T_STEPS - 1;
    const int t1 = (t +  9 < T_STEPS) ? t +  9 : T_STEPS - 1;
    const int t2 = (t + 10 < T_STEPS) ? t + 10 : T_STEPS - 1;
    const int t3 = (t + 11 < T_STEPS) ? t + 11 : T_STEPS - 1;
    const int t4 = (t + 12 < T_STEPS) ? t + 12 : T_STEPS - 1;
    const int t5 = (t + 13 < T_STEPS) ? t + 13 : T_STEPS - 1;
    const int t6 = (t + 14 < T_STEPS) ? t + 14 : T_STEPS - 1;
    const int t7 = (t + 15 < T_STEPS) ? t + 15 : T_STEPS - 1;
    SLOT(B0, B1, t0);
    SLOT(B1, B2, t1);
    SLOT(B2, B3, t2);
    SLOT(B3, B4, t3);
    SLOT(B4, B5, t4);
    SLOT(B5, B6, t5);
    SLOT(B6, B7, t6);
    SLOT(B7, B0, t7);
  }
#undef SLOT
#undef WAIT36

  asm volatile("s_waitcnt vmcnt(0)" ::: "memory");
  {
    f32x4* So4 = reinterpret_cast<f32x4*>(
        S_out + ((size_t)batch * ND + row) * ND + cc * 8);
    f32x4 s0, s1;
    s0.x = S2[0].x; s0.y = S2[0].y; s0.z = S2[1].x; s0.w = S2[1].y;
    s1.x = S2[2].x; s1.y = S2[2].y; s1.z = S2[3].x; s1.w = S2[3].y;
    So4[0] = s0; So4[1] = s1;
  }
}

extern "C" void kernel_launch(void* const* d_in, const int* in_sizes, int n_in,
                              void* d_out, int out_size, void* d_ws, size_t ws_size,
                              hipStream_t stream) {
  const float* x  = (const float*)d_in[0];   // [2048][16][1024]
  const float* S0 = (const float*)d_in[1];   // [16][128][128]
  const float* Wk = (const float*)d_in[2];
  const float* Wv = (const float*)d_in[3];
  const float* Wq = (const float*)d_in[4];
  const float* Wb = (const float*)d_in[5];
  const float* db = (const float*)d_in[6];
  const float* bb = (const float*)d_in[7];
  float* out  = (float*)d_out;                           // [2048][16][128]
  float* Sout = out + (size_t)T_STEPS * NB * ND;         // [16][128][128]
  float* proj = (float*)d_ws;                            // [32768][512] = 64 MB

  dim3 ggrid(256, 4);
  proj_gemm<<<ggrid, 256, 0, stream>>>(x, Wk, Wv, Wq, Wb, proj);
  norm_k<<<8192, 256, 0, stream>>>(proj);
  scan_kernel<<<512, 64, 0, stream>>>(proj, S0, db, bb, out, Sout);
}